// Round 13
// baseline (195.289 us; speedup 1.0000x reference)
//
#include <hip/hip_runtime.h>

#define HIDDEN 16
// ---- medium-bucket sorted-CSR path ----
#define MB 512          // nodes per bucket (power of two)
#define MB_SHIFT 9
#define NMB_MAX 1024    // LDS limit for hist/fill (n <= 524288)
#define MCHUNK 8192     // edges per block in hist/fill
#define MTH 512         // threads in hist/fill blocks
// ---- fallback (split) path ----
#define CB 1024
#define CB_SHIFT 10
#define NCB_MAX 512
#define CHUNK 4096
#define SPL 8
#define BT 1024

// ======================= medium-bucket path =======================

__global__ void k_zerom(unsigned int* cntc, int nmb) {
    int i = blockIdx.x * blockDim.x + threadIdx.x;
    if (i < nmb) cntc[i] = 0u;
}

// per-chunk per-bucket histogram -> hcT[bucket*nchunk + chunk] + totals
__global__ __launch_bounds__(MTH) void
k_histm(const int* __restrict__ dst, int e, int nmb, int nchunk,
        unsigned int* __restrict__ cntc, unsigned int* __restrict__ hcT) {
    __shared__ unsigned int h[NMB_MAX];
    for (int i = threadIdx.x; i < nmb; i += MTH) h[i] = 0u;
    __syncthreads();
    int start = blockIdx.x * MCHUNK;
    int end = min(start + MCHUNK, e);
    int i = start + threadIdx.x;
    for (; i + 3 * MTH < end; i += 4 * MTH) {
        unsigned d0 = dst[i], d1 = dst[i + MTH], d2 = dst[i + 2 * MTH], d3 = dst[i + 3 * MTH];
        atomicAdd(&h[d0 >> MB_SHIFT], 1u);
        atomicAdd(&h[d1 >> MB_SHIFT], 1u);
        atomicAdd(&h[d2 >> MB_SHIFT], 1u);
        atomicAdd(&h[d3 >> MB_SHIFT], 1u);
    }
    for (; i < end; i += MTH)
        atomicAdd(&h[((unsigned)dst[i]) >> MB_SHIFT], 1u);
    __syncthreads();
    for (int j = threadIdx.x; j < nmb; j += MTH) {
        hcT[(size_t)j * nchunk + blockIdx.x] = h[j];
        if (h[j]) atomicAdd(&cntc[j], h[j]);
    }
}

// exclusive scan of bucket totals -> basec (+ sentinels)
__global__ __launch_bounds__(1024) void
k_scanm(const unsigned int* __restrict__ cntc, int nmb,
        unsigned int* __restrict__ basec,
        unsigned int* __restrict__ rowptr, int n, unsigned int e) {
    __shared__ unsigned int tsum[1024];
    int t = threadIdx.x;
    int K = (nmb + 1023) / 1024;
    unsigned int s = 0;
    for (int k = 0; k < K; k++) {
        int i = t * K + k;
        if (i < nmb) s += cntc[i];
    }
    tsum[t] = s;
    __syncthreads();
    for (int off = 1; off < 1024; off <<= 1) {
        unsigned int v = (t >= off) ? tsum[t - off] : 0u;
        __syncthreads();
        tsum[t] += v;
        __syncthreads();
    }
    unsigned int run = (t == 0) ? 0u : tsum[t - 1];
    for (int k = 0; k < K; k++) {
        int i = t * K + k;
        if (i < nmb) { basec[i] = run; run += cntc[i]; }
    }
    if (t == 1023) basec[nmb] = tsum[1023];   // == e
    if (t == 0) rowptr[n] = e;                // CSR sentinel
}

// per-bucket scan over chunks: lbasec[b*nchunk + c] = basec[b] + prefix(hcT)
__global__ void k_scancm(const unsigned int* __restrict__ hcT,
                         const unsigned int* __restrict__ basec,
                         unsigned int* __restrict__ lbasec, int nchunk) {
    __shared__ unsigned int ts[256];
    __shared__ unsigned int carry;
    int b = blockIdx.x, t = threadIdx.x;
    if (t == 0) carry = basec[b];
    __syncthreads();
    for (int t0 = 0; t0 < nchunk; t0 += 256) {
        int i = t0 + t;
        unsigned int v = (i < nchunk) ? hcT[(size_t)b * nchunk + i] : 0u;
        ts[t] = v;
        __syncthreads();
        for (int off = 1; off < 256; off <<= 1) {
            unsigned int u = (t >= off) ? ts[t - off] : 0u;
            __syncthreads();
            ts[t] += u;
            __syncthreads();
        }
        if (i < nchunk) lbasec[(size_t)b * nchunk + i] = carry + ts[t] - v;
        __syncthreads();
        if (t == 0) carry += ts[255];
        __syncthreads();
    }
}

// scatter records (src<<9 | dst&511): runs of ~42 records -> ~1.3x write amp
__global__ __launch_bounds__(MTH) void
k_fillm(const int* __restrict__ src, const int* __restrict__ dst,
        int e, int nmb, int nchunk,
        const unsigned int* __restrict__ lbasec,
        unsigned int* __restrict__ tmp) {
    __shared__ unsigned int h[NMB_MAX];
    __shared__ unsigned int lb[NMB_MAX];
    for (int j = threadIdx.x; j < nmb; j += MTH) {
        lb[j] = lbasec[(size_t)j * nchunk + blockIdx.x];
        h[j] = 0u;
    }
    __syncthreads();
    int start = blockIdx.x * MCHUNK;
    int end = min(start + MCHUNK, e);
    for (int i = start + threadIdx.x; i < end; i += MTH) {
        unsigned int d = (unsigned)dst[i];
        unsigned int s = (unsigned)src[i];
        unsigned int b = d >> MB_SHIFT;
        unsigned int r = atomicAdd(&h[b], 1u);
        tmp[lb[b] + r] = (s << MB_SHIFT) | (d & (MB - 1u));
    }
}

// FUSED per-bucket counting sort: count -> scan -> rowptr+xs4 -> scatter.
// One 512-thread block per 512-node bucket (196 blocks); segment ~64 KB
// stays L2-hot between passes; scatter confined to 64 KB window.
__global__ __launch_bounds__(MB) void
k_sortC(const unsigned int* __restrict__ tmp,
        const unsigned int* __restrict__ basec,
        const float* __restrict__ x,
        unsigned int* __restrict__ rowptr, unsigned int* __restrict__ tmp2,
        float4* __restrict__ xs4, int n) {
    __shared__ unsigned int cnt[MB];
    __shared__ unsigned int sc[MB];
    __shared__ unsigned int cur[MB];
    int t = threadIdx.x, b = blockIdx.x;
    unsigned int s = basec[b], endp = basec[b + 1];
    cnt[t] = 0u;
    __syncthreads();
    for (unsigned int i = s + t; i < endp; i += MB)        // pass A: count
        atomicAdd(&cnt[tmp[i] & (MB - 1u)], 1u);
    __syncthreads();
    sc[t] = cnt[t];
    __syncthreads();
    for (int off = 1; off < MB; off <<= 1) {               // inclusive scan
        unsigned int v = (t >= off) ? sc[t - off] : 0u;
        __syncthreads();
        sc[t] += v;
        __syncthreads();
    }
    unsigned int excl = sc[t] - cnt[t];
    cur[t] = s + excl;
    int node = (b << MB_SHIFT) + t;
    if (node < n) {
        rowptr[node] = s + excl;
        float iv = rsqrtf((float)(1u + cnt[t]));           // +1 self-loop
        xs4[node] = make_float4(x[3 * node] * iv, x[3 * node + 1] * iv,
                                x[3 * node + 2] * iv, iv);
    }
    __syncthreads();
    for (unsigned int i = s + t; i < endp; i += MB) {      // pass B: scatter
        unsigned int rec = tmp[i];                         // L2-hot re-read
        unsigned int r = atomicAdd(&cur[rec & (MB - 1u)], 1u);
        tmp2[r] = rec >> MB_SHIFT;                         // src id
    }
}

// layer-1: two threads per node, pair-combine via shfl_xor, fused epilogue
__global__ void k_s1(const unsigned int* __restrict__ rowptr,
                     const unsigned int* __restrict__ tmp2,
                     const float4* __restrict__ xs4,
                     const float* __restrict__ W1, const float* __restrict__ b1,
                     const float* __restrict__ W2, const float* __restrict__ b2,
                     float* __restrict__ t2s, float* __restrict__ out, int n) {
    int gid = blockIdx.x * blockDim.x + threadIdx.x;
    int i = gid >> 1, h = gid & 1;
    bool valid = (i < n);
    unsigned int s = 0, epos = 0;
    if (valid) { s = rowptr[i]; epos = rowptr[i + 1]; }
    unsigned int half = (epos - s) >> 1;
    unsigned int b0 = h ? s + half : s;
    unsigned int b1r = h ? epos : s + half;
    float v0 = 0.f, v1 = 0.f, v2 = 0.f;
    unsigned int j = b0;
    for (; j + 4 <= b1r; j += 4) {
        unsigned a0 = tmp2[j], a1 = tmp2[j + 1], a2 = tmp2[j + 2], a3 = tmp2[j + 3];
        float4 p0 = xs4[a0], p1 = xs4[a1], p2 = xs4[a2], p3 = xs4[a3];
        v0 += (p0.x + p1.x) + (p2.x + p3.x);
        v1 += (p0.y + p1.y) + (p2.y + p3.y);
        v2 += (p0.z + p1.z) + (p2.z + p3.z);
    }
    for (; j < b1r; j++) {
        float4 p = xs4[tmp2[j]];
        v0 += p.x; v1 += p.y; v2 += p.z;
    }
    v0 += __shfl_xor(v0, 1);
    v1 += __shfl_xor(v1, 1);
    v2 += __shfl_xor(v2, 1);
    if (valid && h == 0) {
        float4 me = xs4[i];
        float iv = me.w;
        v0 = (v0 + me.x) * iv;
        v1 = (v1 + me.y) * iv;
        v2 = (v2 + me.z) * iv;
        float acc = 0.f;
#pragma unroll
        for (int k = 0; k < HIDDEN; k++) {
            float hh = fmaxf(fmaf(v0, W1[k], fmaf(v1, W1[HIDDEN + k],
                            fmaf(v2, W1[2 * HIDDEN + k], b1[k]))), 0.f);
            acc += hh * W2[k];
        }
        t2s[i] = acc * iv;
        out[i] = b2[0] + acc * iv * iv;
    }
}

// layer-2: two threads per node, scalar gathers of t2s, pair-combine
__global__ void k_s2(const unsigned int* __restrict__ rowptr,
                     const unsigned int* __restrict__ tmp2,
                     const float* __restrict__ t2s, const float4* __restrict__ xs4,
                     float* __restrict__ out, int n) {
    int gid = blockIdx.x * blockDim.x + threadIdx.x;
    int i = gid >> 1, h = gid & 1;
    bool valid = (i < n);
    unsigned int s = 0, epos = 0;
    if (valid) { s = rowptr[i]; epos = rowptr[i + 1]; }
    unsigned int half = (epos - s) >> 1;
    unsigned int b0 = h ? s + half : s;
    unsigned int b1r = h ? epos : s + half;
    float v = 0.f;
    unsigned int j = b0;
    for (; j + 4 <= b1r; j += 4) {
        unsigned a0 = tmp2[j], a1 = tmp2[j + 1], a2 = tmp2[j + 2], a3 = tmp2[j + 3];
        v += (t2s[a0] + t2s[a1]) + (t2s[a2] + t2s[a3]);
    }
    for (; j < b1r; j++) v += t2s[tmp2[j]];
    v += __shfl_xor(v, 1);
    if (valid && h == 0) out[i] += v * xs4[i].w;
}

// ======================= split fallback backend (R10) =======================

__global__ void k_zero(unsigned int* a, int na) {
    int i = blockIdx.x * blockDim.x + threadIdx.x;
    if (i < na) a[i] = 0u;
}
__global__ void k_hist_c(const int* __restrict__ dst, int e, int ncb, int nchunk,
                         unsigned int* __restrict__ cntc,
                         unsigned int* __restrict__ hcT) {
    __shared__ unsigned int h[NCB_MAX];
    for (int i = threadIdx.x; i < ncb; i += blockDim.x) h[i] = 0u;
    __syncthreads();
    int start = blockIdx.x * CHUNK;
    int end = min(start + CHUNK, e);
    for (int i = start + threadIdx.x; i < end; i += 256)
        atomicAdd(&h[((unsigned)dst[i]) >> CB_SHIFT], 1u);
    __syncthreads();
    for (int j = threadIdx.x; j < ncb; j += blockDim.x) {
        hcT[(size_t)j * nchunk + blockIdx.x] = h[j];
        if (h[j]) atomicAdd(&cntc[j], h[j]);
    }
}
__global__ void k_scan(const unsigned int* __restrict__ cnt, int nb,
                       unsigned int* __restrict__ base) {
    __shared__ unsigned int tsum[256];
    int t = threadIdx.x;
    int K = (nb + 255) / 256;
    unsigned int s = 0;
    for (int k = 0; k < K; k++) {
        int i = t * K + k;
        if (i < nb) s += cnt[i];
    }
    tsum[t] = s;
    __syncthreads();
    for (int off = 1; off < 256; off <<= 1) {
        unsigned int v = (t >= off) ? tsum[t - off] : 0u;
        __syncthreads();
        tsum[t] += v;
        __syncthreads();
    }
    unsigned int run = (t == 0) ? 0u : tsum[t - 1];
    for (int k = 0; k < K; k++) {
        int i = t * K + k;
        if (i < nb) { base[i] = run; run += cnt[i]; }
    }
}
__global__ void k_scanc(const unsigned int* __restrict__ hcT,
                        const unsigned int* __restrict__ basec,
                        unsigned int* __restrict__ lbasec, int nchunk) {
    __shared__ unsigned int ts[256];
    __shared__ unsigned int carry;
    int b = blockIdx.x, t = threadIdx.x;
    if (t == 0) carry = basec[b];
    __syncthreads();
    for (int t0 = 0; t0 < nchunk; t0 += 256) {
        int i = t0 + t;
        unsigned int v = (i < nchunk) ? hcT[(size_t)b * nchunk + i] : 0u;
        ts[t] = v;
        __syncthreads();
        for (int off = 1; off < 256; off <<= 1) {
            unsigned int u = (t >= off) ? ts[t - off] : 0u;
            __syncthreads();
            ts[t] += u;
            __syncthreads();
        }
        if (i < nchunk) lbasec[(size_t)b * nchunk + i] = carry + ts[t] - v;
        __syncthreads();
        if (t == 0) carry += ts[255];
        __syncthreads();
    }
}
__global__ void k_fill_c(const int* __restrict__ src, const int* __restrict__ dst,
                         int e, int ncb, int nchunk,
                         const unsigned int* __restrict__ lbasec,
                         unsigned int* __restrict__ tmp) {
    __shared__ unsigned int h[NCB_MAX];
    __shared__ unsigned int lb[NCB_MAX];
    for (int j = threadIdx.x; j < ncb; j += blockDim.x) {
        lb[j] = lbasec[(size_t)j * nchunk + blockIdx.x];
        h[j] = 0u;
    }
    __syncthreads();
    int start = blockIdx.x * CHUNK;
    int end = min(start + CHUNK, e);
    for (int i = start + threadIdx.x; i < end; i += 256) {
        unsigned int d = (unsigned)dst[i];
        unsigned int b = d >> CB_SHIFT;
        unsigned int r = atomicAdd(&h[b], 1u);
        tmp[lb[b] + r] = (((unsigned)src[i]) << CB_SHIFT) | (d & (CB - 1u));
    }
}
__global__ __launch_bounds__(BT) void
k_deg_split(const unsigned int* __restrict__ tmp, const unsigned int* __restrict__ basec,
            const unsigned int* __restrict__ cntc, unsigned int* __restrict__ deg, int n) {
    __shared__ unsigned int degl[CB];
    int t = threadIdx.x;
    degl[t] = 0u;
    __syncthreads();
    int b = blockIdx.x / SPL, sl = blockIdx.x % SPL;
    unsigned int s = basec[b], m = cntc[b];
    for (unsigned int i = sl * BT + t; i < m; i += SPL * BT)
        atomicAdd(&degl[tmp[s + i] & (CB - 1u)], 1u);
    __syncthreads();
    int node = b * CB + t;
    unsigned int c = degl[t];
    if (node < n && c) atomicAdd(&deg[node], c);
}
__global__ void k_inv_s(const unsigned int* __restrict__ deg, const float* __restrict__ x,
                        float4* __restrict__ xs4, int n) {
    int i = blockIdx.x * blockDim.x + threadIdx.x;
    if (i >= n) return;
    float iv = rsqrtf((float)(deg[i] + 1u));
    xs4[i] = make_float4(x[3 * i] * iv, x[3 * i + 1] * iv, x[3 * i + 2] * iv, iv);
}
__global__ __launch_bounds__(BT) void
k_s1_split(const unsigned int* __restrict__ tmp, const unsigned int* __restrict__ basec,
           const unsigned int* __restrict__ cntc, const float4* __restrict__ xs4,
           float* __restrict__ agg0, float* __restrict__ agg1, float* __restrict__ agg2, int n) {
    __shared__ float a0[CB], a1[CB], a2[CB];
    int t = threadIdx.x;
    a0[t] = 0.f; a1[t] = 0.f; a2[t] = 0.f;
    __syncthreads();
    int b = blockIdx.x / SPL, sl = blockIdx.x % SPL;
    unsigned int s = basec[b], m = cntc[b];
    for (unsigned int i = sl * BT + t; i < m; i += SPL * BT) {
        unsigned rec = tmp[s + i];
        float4 v = xs4[rec >> CB_SHIFT];
        unsigned dl = rec & (CB - 1u);
        atomicAdd(&a0[dl], v.x); atomicAdd(&a1[dl], v.y); atomicAdd(&a2[dl], v.z);
    }
    __syncthreads();
    int node = b * CB + t;
    if (node < n) {
        if (a0[t] != 0.f) atomicAdd(&agg0[node], a0[t]);
        if (a1[t] != 0.f) atomicAdd(&agg1[node], a1[t]);
        if (a2[t] != 0.f) atomicAdd(&agg2[node], a2[t]);
    }
}
__global__ void k_epi_s(const float* __restrict__ agg0, const float* __restrict__ agg1,
                        const float* __restrict__ agg2, const float4* __restrict__ xs4,
                        const float* __restrict__ W1, const float* __restrict__ b1,
                        const float* __restrict__ W2, const float* __restrict__ b2,
                        float* __restrict__ t2s, float* __restrict__ out, int n) {
    int i = blockIdx.x * blockDim.x + threadIdx.x;
    if (i >= n) return;
    float4 xv = xs4[i];
    float iv = xv.w;
    float v0 = iv * (agg0[i] + xv.x), v1 = iv * (agg1[i] + xv.y), v2 = iv * (agg2[i] + xv.z);
    float acc = 0.f;
#pragma unroll
    for (int j = 0; j < HIDDEN; j++) {
        float h = fmaxf(fmaf(v0, W1[j], fmaf(v1, W1[HIDDEN + j],
                       fmaf(v2, W1[2 * HIDDEN + j], b1[j]))), 0.f);
        acc += h * W2[j];
    }
    t2s[i] = acc * iv;
    out[i] = b2[0] + acc * iv * iv;
}
__global__ __launch_bounds__(BT) void
k_s2_split(const unsigned int* __restrict__ tmp, const unsigned int* __restrict__ basec,
           const unsigned int* __restrict__ cntc, const float* __restrict__ t2s,
           const float4* __restrict__ xs4, float* __restrict__ out, int n) {
    __shared__ float o[CB];
    int t = threadIdx.x;
    o[t] = 0.f;
    __syncthreads();
    int b = blockIdx.x / SPL, sl = blockIdx.x % SPL;
    unsigned int s = basec[b], m = cntc[b];
    for (unsigned int i = sl * BT + t; i < m; i += SPL * BT) {
        unsigned rec = tmp[s + i];
        atomicAdd(&o[rec & (CB - 1u)], t2s[rec >> CB_SHIFT]);
    }
    __syncthreads();
    int node = b * CB + t;
    if (node < n && o[t] != 0.f) atomicAdd(&out[node], o[t] * xs4[node].w);
}

// ======================= launch =======================

extern "C" void kernel_launch(void* const* d_in, const int* in_sizes, int n_in,
                              void* d_out, int out_size, void* d_ws, size_t ws_size,
                              hipStream_t stream) {
    const float* x  = (const float*)d_in[0];
    const int*   ei = (const int*)d_in[1];
    const float* W1 = (const float*)d_in[2];
    const float* b1 = (const float*)d_in[3];
    const float* W2 = (const float*)d_in[4];
    const float* b2 = (const float*)d_in[5];
    float* out = (float*)d_out;

    int n = in_sizes[0] / 3;
    int e = in_sizes[1] / 2;
    const int* src = ei;
    const int* dst = ei + e;
    const int B = 256;

    int nmb = (n + MB - 1) / MB;
    int nchunkm = (e + MCHUNK - 1) / MCHUNK;
    int gridN2 = (2 * n + B - 1) / B;

    // ws: xs4[n] | t2s[n] | rowptr[n+1] | cntc[nmb] basec[nmb+1]
    //   | hcT[nmb*nchunkm] | lbasec[nmb*nchunkm] | tmp[e] | tmp2[e]
    size_t needm = (size_t)n * 16 + (size_t)n * 4 + (size_t)(n + 1) * 4
                 + (size_t)(2 * nmb + 1) * 4 + (size_t)nmb * nchunkm * 8
                 + (size_t)e * 8 + 64;

    if (nmb <= NMB_MAX && n < (1 << 23) && ws_size >= needm) {
        float4* xs4 = (float4*)d_ws;                            // n
        float* t2s = (float*)(xs4 + n);                         // n
        unsigned int* rowptr = (unsigned int*)(t2s + n);        // n+1
        unsigned int* cntc   = rowptr + (n + 1);                // nmb
        unsigned int* basec  = cntc + nmb;                      // nmb+1
        unsigned int* hcT    = basec + nmb + 1;                 // nmb*nchunkm
        unsigned int* lbasec = hcT + (size_t)nmb * nchunkm;     // nmb*nchunkm
        unsigned int* tmp    = lbasec + (size_t)nmb * nchunkm;  // e
        unsigned int* tmp2   = tmp + e;                         // e

        k_zerom<<<(nmb + B - 1) / B, B, 0, stream>>>(cntc, nmb);
        k_histm<<<nchunkm, MTH, 0, stream>>>(dst, e, nmb, nchunkm, cntc, hcT);
        k_scanm<<<1, 1024, 0, stream>>>(cntc, nmb, basec, rowptr, n, (unsigned)e);
        k_scancm<<<nmb, 256, 0, stream>>>(hcT, basec, lbasec, nchunkm);
        k_fillm<<<nchunkm, MTH, 0, stream>>>(src, dst, e, nmb, nchunkm, lbasec, tmp);
        k_sortC<<<nmb, MB, 0, stream>>>(tmp, basec, x, rowptr, tmp2, xs4, n);
        k_s1<<<gridN2, B, 0, stream>>>(rowptr, tmp2, xs4, W1, b1, W2, b2, t2s, out, n);
        k_s2<<<gridN2, B, 0, stream>>>(rowptr, tmp2, t2s, xs4, out, n);
    } else {
        int ncb = (n + CB - 1) / CB;
        int gridE = (e + CHUNK - 1) / CHUNK;
        int gridN = (n + B - 1) / B;
        float4* xs4 = (float4*)d_ws;
        float* agg0 = (float*)(xs4 + n);
        float* agg1 = agg0 + n;
        float* agg2 = agg1 + n;
        unsigned int* deg = (unsigned int*)(agg2 + n);
        float* t2s = (float*)(deg + n);
        unsigned int* cntc   = (unsigned int*)(t2s + n);
        unsigned int* basec  = cntc + ncb;
        unsigned int* hcT    = basec + ncb;
        unsigned int* lbasec = hcT + (size_t)ncb * gridE;
        unsigned int* tmp    = lbasec + (size_t)ncb * gridE;

        k_zero<<<(4 * n + ncb + B - 1) / B, B, 0, stream>>>((unsigned int*)agg0, 4 * n);
        k_zero<<<(ncb + B - 1) / B, B, 0, stream>>>(cntc, ncb);
        k_hist_c<<<gridE, B, 0, stream>>>(dst, e, ncb, gridE, cntc, hcT);
        k_scan<<<1, B, 0, stream>>>(cntc, ncb, basec);
        k_scanc<<<ncb, B, 0, stream>>>(hcT, basec, lbasec, gridE);
        k_fill_c<<<gridE, B, 0, stream>>>(src, dst, e, ncb, gridE, lbasec, tmp);
        k_deg_split<<<ncb * SPL, BT, 0, stream>>>(tmp, basec, cntc, deg, n);
        k_inv_s<<<gridN, B, 0, stream>>>(deg, x, xs4, n);
        k_s1_split<<<ncb * SPL, BT, 0, stream>>>(tmp, basec, cntc, xs4, agg0, agg1, agg2, n);
        k_epi_s<<<gridN, B, 0, stream>>>(agg0, agg1, agg2, xs4, W1, b1, W2, b2, t2s, out, n);
        k_s2_split<<<ncb * SPL, BT, 0, stream>>>(tmp, basec, cntc, t2s, xs4, out, n);
    }
}

// Round 14
// 193.028 us; speedup vs baseline: 1.0117x; 1.0117x over previous
//
#include <hip/hip_runtime.h>

#define HIDDEN 16
// ---- 1024-bucket sorted-CSR path ----
#define CB 1024         // nodes per bucket (power of two)
#define CB_SHIFT 10
#define NCB_MAX 512     // LDS limit for hist/fill buckets
#define CHUNK 4096      // edges per block in hist/fill (R10-proven)
#define BT 1024
// ---- fallback (split) path ----
#define SPL 8

// ======================= sorted-CSR path =======================

// per-chunk per-bucket histogram -> hcT[bucket*nchunk + chunk]; NO atomics
__global__ void k_hist(const int* __restrict__ dst, int e, int ncb, int nchunk,
                       unsigned int* __restrict__ hcT) {
    __shared__ unsigned int h[NCB_MAX];
    for (int i = threadIdx.x; i < ncb; i += blockDim.x) h[i] = 0u;
    __syncthreads();
    int start = blockIdx.x * CHUNK;
    int end = min(start + CHUNK, e);
    int i = start + threadIdx.x;
    for (; i + 3 * 256 < end; i += 4 * 256) {
        unsigned d0 = dst[i], d1 = dst[i + 256], d2 = dst[i + 512], d3 = dst[i + 768];
        atomicAdd(&h[d0 >> CB_SHIFT], 1u);
        atomicAdd(&h[d1 >> CB_SHIFT], 1u);
        atomicAdd(&h[d2 >> CB_SHIFT], 1u);
        atomicAdd(&h[d3 >> CB_SHIFT], 1u);
    }
    for (; i < end; i += 256)
        atomicAdd(&h[((unsigned)dst[i]) >> CB_SHIFT], 1u);
    __syncthreads();
    for (int j = threadIdx.x; j < ncb; j += blockDim.x)
        hcT[(size_t)j * nchunk + blockIdx.x] = h[j];
}

// one block per bucket: in-place exclusive scan of hcT row; total -> cntc[b]
__global__ void k_scanf(unsigned int* __restrict__ hcT,
                        unsigned int* __restrict__ cntc, int nchunk) {
    __shared__ unsigned int ts[256];
    __shared__ unsigned int carry;
    int b = blockIdx.x, t = threadIdx.x;
    if (t == 0) carry = 0u;
    __syncthreads();
    size_t row = (size_t)b * nchunk;
    for (int t0 = 0; t0 < nchunk; t0 += 256) {
        int i = t0 + t;
        unsigned int v = (i < nchunk) ? hcT[row + i] : 0u;
        ts[t] = v;
        __syncthreads();
        for (int off = 1; off < 256; off <<= 1) {
            unsigned int u = (t >= off) ? ts[t - off] : 0u;
            __syncthreads();
            ts[t] += u;
            __syncthreads();
        }
        if (i < nchunk) hcT[row + i] = carry + ts[t] - v;
        __syncthreads();
        if (t == 0) carry += ts[255];
        __syncthreads();
    }
    if (t == 0) cntc[b] = carry;
}

// scan bucket totals -> basec (+ sentinels)
__global__ __launch_bounds__(256) void
k_scanb(const unsigned int* __restrict__ cntc, int ncb,
        unsigned int* __restrict__ basec,
        unsigned int* __restrict__ rowptr, int n, unsigned int e) {
    __shared__ unsigned int tsum[256];
    int t = threadIdx.x;
    unsigned int s = (t < ncb) ? cntc[t] : 0u;   // ncb <= 256 assumed here
    tsum[t] = s;
    __syncthreads();
    for (int off = 1; off < 256; off <<= 1) {
        unsigned int v = (t >= off) ? tsum[t - off] : 0u;
        __syncthreads();
        tsum[t] += v;
        __syncthreads();
    }
    if (t < ncb) basec[t] = tsum[t] - s;
    if (t == 255) basec[ncb] = tsum[255];        // == e
    if (t == 0) rowptr[n] = e;                   // CSR sentinel
}

// scatter records (src<<10 | dst_local) using precomputed bases
__global__ void k_fill(const int* __restrict__ src, const int* __restrict__ dst,
                       int e, int ncb, int nchunk,
                       const unsigned int* __restrict__ basec,
                       const unsigned int* __restrict__ hcT,
                       unsigned int* __restrict__ tmp) {
    __shared__ unsigned int h[NCB_MAX];
    __shared__ unsigned int lb[NCB_MAX];
    for (int j = threadIdx.x; j < ncb; j += blockDim.x) {
        lb[j] = basec[j] + hcT[(size_t)j * nchunk + blockIdx.x];
        h[j] = 0u;
    }
    __syncthreads();
    int start = blockIdx.x * CHUNK;
    int end = min(start + CHUNK, e);
    for (int i = start + threadIdx.x; i < end; i += 256) {
        unsigned int d = (unsigned)dst[i];
        unsigned int s = (unsigned)src[i];
        unsigned int b = d >> CB_SHIFT;
        unsigned int r = atomicAdd(&h[b], 1u);
        tmp[lb[b] + r] = (s << CB_SHIFT) | (d & (CB - 1u));
    }
}

// FUSED per-bucket counting sort: count -> scan -> rowptr+xs4 -> scatter.
// One 1024-thread block per 1024-node bucket (98 blocks, 16 waves each);
// 128 KB segment stays L2-hot between passes; scatter in 128 KB window.
__global__ __launch_bounds__(BT) void
k_sortC(const unsigned int* __restrict__ tmp,
        const unsigned int* __restrict__ basec,
        const float* __restrict__ x,
        unsigned int* __restrict__ rowptr, unsigned int* __restrict__ tmp2,
        float4* __restrict__ xs4, int n) {
    __shared__ unsigned int cnt[CB];
    __shared__ unsigned int sc[CB];
    __shared__ unsigned int cur[CB];
    int t = threadIdx.x, b = blockIdx.x;
    unsigned int s = basec[b], endp = basec[b + 1];
    cnt[t] = 0u;
    __syncthreads();
    for (unsigned int i = s + t; i < endp; i += BT)        // pass A: count
        atomicAdd(&cnt[tmp[i] & (CB - 1u)], 1u);
    __syncthreads();
    sc[t] = cnt[t];
    __syncthreads();
    for (int off = 1; off < CB; off <<= 1) {               // inclusive scan
        unsigned int v = (t >= off) ? sc[t - off] : 0u;
        __syncthreads();
        sc[t] += v;
        __syncthreads();
    }
    unsigned int excl = sc[t] - cnt[t];
    cur[t] = s + excl;
    int node = (b << CB_SHIFT) + t;
    if (node < n) {
        rowptr[node] = s + excl;
        float iv = rsqrtf((float)(1u + cnt[t]));           // +1 self-loop
        xs4[node] = make_float4(x[3 * node] * iv, x[3 * node + 1] * iv,
                                x[3 * node + 2] * iv, iv);
    }
    __syncthreads();
    for (unsigned int i = s + t; i < endp; i += BT) {      // pass B: scatter
        unsigned int rec = tmp[i];                         // L2-hot re-read
        unsigned int r = atomicAdd(&cur[rec & (CB - 1u)], 1u);
        tmp2[r] = rec >> CB_SHIFT;                         // src id
    }
}

// layer-1: two threads per node, pair-combine via shfl_xor, fused epilogue
__global__ void k_s1(const unsigned int* __restrict__ rowptr,
                     const unsigned int* __restrict__ tmp2,
                     const float4* __restrict__ xs4,
                     const float* __restrict__ W1, const float* __restrict__ b1,
                     const float* __restrict__ W2, const float* __restrict__ b2,
                     float* __restrict__ t2s, float* __restrict__ out, int n) {
    int gid = blockIdx.x * blockDim.x + threadIdx.x;
    int i = gid >> 1, h = gid & 1;
    bool valid = (i < n);
    unsigned int s = 0, epos = 0;
    if (valid) { s = rowptr[i]; epos = rowptr[i + 1]; }
    unsigned int half = (epos - s) >> 1;
    unsigned int b0 = h ? s + half : s;
    unsigned int b1r = h ? epos : s + half;
    float v0 = 0.f, v1 = 0.f, v2 = 0.f;
    unsigned int j = b0;
    for (; j + 4 <= b1r; j += 4) {
        unsigned a0 = tmp2[j], a1 = tmp2[j + 1], a2 = tmp2[j + 2], a3 = tmp2[j + 3];
        float4 p0 = xs4[a0], p1 = xs4[a1], p2 = xs4[a2], p3 = xs4[a3];
        v0 += (p0.x + p1.x) + (p2.x + p3.x);
        v1 += (p0.y + p1.y) + (p2.y + p3.y);
        v2 += (p0.z + p1.z) + (p2.z + p3.z);
    }
    for (; j < b1r; j++) {
        float4 p = xs4[tmp2[j]];
        v0 += p.x; v1 += p.y; v2 += p.z;
    }
    v0 += __shfl_xor(v0, 1);
    v1 += __shfl_xor(v1, 1);
    v2 += __shfl_xor(v2, 1);
    if (valid && h == 0) {
        float4 me = xs4[i];
        float iv = me.w;
        v0 = (v0 + me.x) * iv;
        v1 = (v1 + me.y) * iv;
        v2 = (v2 + me.z) * iv;
        float acc = 0.f;
#pragma unroll
        for (int k = 0; k < HIDDEN; k++) {
            float hh = fmaxf(fmaf(v0, W1[k], fmaf(v1, W1[HIDDEN + k],
                            fmaf(v2, W1[2 * HIDDEN + k], b1[k]))), 0.f);
            acc += hh * W2[k];
        }
        t2s[i] = acc * iv;
        out[i] = b2[0] + acc * iv * iv;
    }
}

// layer-2: two threads per node, scalar gathers of t2s, pair-combine
__global__ void k_s2(const unsigned int* __restrict__ rowptr,
                     const unsigned int* __restrict__ tmp2,
                     const float* __restrict__ t2s, const float4* __restrict__ xs4,
                     float* __restrict__ out, int n) {
    int gid = blockIdx.x * blockDim.x + threadIdx.x;
    int i = gid >> 1, h = gid & 1;
    bool valid = (i < n);
    unsigned int s = 0, epos = 0;
    if (valid) { s = rowptr[i]; epos = rowptr[i + 1]; }
    unsigned int half = (epos - s) >> 1;
    unsigned int b0 = h ? s + half : s;
    unsigned int b1r = h ? epos : s + half;
    float v = 0.f;
    unsigned int j = b0;
    for (; j + 4 <= b1r; j += 4) {
        unsigned a0 = tmp2[j], a1 = tmp2[j + 1], a2 = tmp2[j + 2], a3 = tmp2[j + 3];
        v += (t2s[a0] + t2s[a1]) + (t2s[a2] + t2s[a3]);
    }
    for (; j < b1r; j++) v += t2s[tmp2[j]];
    v += __shfl_xor(v, 1);
    if (valid && h == 0) out[i] += v * xs4[i].w;
}

// ======================= split fallback backend (R10-proven) =======================

__global__ void k_zero(unsigned int* a, int na) {
    int i = blockIdx.x * blockDim.x + threadIdx.x;
    if (i < na) a[i] = 0u;
}
__global__ __launch_bounds__(BT) void
k_deg_split(const unsigned int* __restrict__ tmp, const unsigned int* __restrict__ basec,
            const unsigned int* __restrict__ cntc, unsigned int* __restrict__ deg, int n) {
    __shared__ unsigned int degl[CB];
    int t = threadIdx.x;
    degl[t] = 0u;
    __syncthreads();
    int b = blockIdx.x / SPL, sl = blockIdx.x % SPL;
    unsigned int s = basec[b], m = cntc[b];
    for (unsigned int i = sl * BT + t; i < m; i += SPL * BT)
        atomicAdd(&degl[tmp[s + i] & (CB - 1u)], 1u);
    __syncthreads();
    int node = b * CB + t;
    unsigned int c = degl[t];
    if (node < n && c) atomicAdd(&deg[node], c);
}
__global__ void k_inv_s(const unsigned int* __restrict__ deg, const float* __restrict__ x,
                        float4* __restrict__ xs4, int n) {
    int i = blockIdx.x * blockDim.x + threadIdx.x;
    if (i >= n) return;
    float iv = rsqrtf((float)(deg[i] + 1u));
    xs4[i] = make_float4(x[3 * i] * iv, x[3 * i + 1] * iv, x[3 * i + 2] * iv, iv);
}
__global__ __launch_bounds__(BT) void
k_s1_split(const unsigned int* __restrict__ tmp, const unsigned int* __restrict__ basec,
           const unsigned int* __restrict__ cntc, const float4* __restrict__ xs4,
           float* __restrict__ agg0, float* __restrict__ agg1, float* __restrict__ agg2, int n) {
    __shared__ float a0[CB], a1[CB], a2[CB];
    int t = threadIdx.x;
    a0[t] = 0.f; a1[t] = 0.f; a2[t] = 0.f;
    __syncthreads();
    int b = blockIdx.x / SPL, sl = blockIdx.x % SPL;
    unsigned int s = basec[b], m = cntc[b];
    for (unsigned int i = sl * BT + t; i < m; i += SPL * BT) {
        unsigned rec = tmp[s + i];
        float4 v = xs4[rec >> CB_SHIFT];
        unsigned dl = rec & (CB - 1u);
        atomicAdd(&a0[dl], v.x); atomicAdd(&a1[dl], v.y); atomicAdd(&a2[dl], v.z);
    }
    __syncthreads();
    int node = b * CB + t;
    if (node < n) {
        if (a0[t] != 0.f) atomicAdd(&agg0[node], a0[t]);
        if (a1[t] != 0.f) atomicAdd(&agg1[node], a1[t]);
        if (a2[t] != 0.f) atomicAdd(&agg2[node], a2[t]);
    }
}
__global__ void k_epi_s(const float* __restrict__ agg0, const float* __restrict__ agg1,
                        const float* __restrict__ agg2, const float4* __restrict__ xs4,
                        const float* __restrict__ W1, const float* __restrict__ b1,
                        const float* __restrict__ W2, const float* __restrict__ b2,
                        float* __restrict__ t2s, float* __restrict__ out, int n) {
    int i = blockIdx.x * blockDim.x + threadIdx.x;
    if (i >= n) return;
    float4 xv = xs4[i];
    float iv = xv.w;
    float v0 = iv * (agg0[i] + xv.x), v1 = iv * (agg1[i] + xv.y), v2 = iv * (agg2[i] + xv.z);
    float acc = 0.f;
#pragma unroll
    for (int j = 0; j < HIDDEN; j++) {
        float h = fmaxf(fmaf(v0, W1[j], fmaf(v1, W1[HIDDEN + j],
                       fmaf(v2, W1[2 * HIDDEN + j], b1[j]))), 0.f);
        acc += h * W2[j];
    }
    t2s[i] = acc * iv;
    out[i] = b2[0] + acc * iv * iv;
}
__global__ __launch_bounds__(BT) void
k_s2_split(const unsigned int* __restrict__ tmp, const unsigned int* __restrict__ basec,
           const unsigned int* __restrict__ cntc, const float* __restrict__ t2s,
           const float4* __restrict__ xs4, float* __restrict__ out, int n) {
    __shared__ float o[CB];
    int t = threadIdx.x;
    o[t] = 0.f;
    __syncthreads();
    int b = blockIdx.x / SPL, sl = blockIdx.x % SPL;
    unsigned int s = basec[b], m = cntc[b];
    for (unsigned int i = sl * BT + t; i < m; i += SPL * BT) {
        unsigned rec = tmp[s + i];
        atomicAdd(&o[rec & (CB - 1u)], t2s[rec >> CB_SHIFT]);
    }
    __syncthreads();
    int node = b * CB + t;
    if (node < n && o[t] != 0.f) atomicAdd(&out[node], o[t] * xs4[node].w);
}

// ======================= launch =======================

extern "C" void kernel_launch(void* const* d_in, const int* in_sizes, int n_in,
                              void* d_out, int out_size, void* d_ws, size_t ws_size,
                              hipStream_t stream) {
    const float* x  = (const float*)d_in[0];
    const int*   ei = (const int*)d_in[1];
    const float* W1 = (const float*)d_in[2];
    const float* b1 = (const float*)d_in[3];
    const float* W2 = (const float*)d_in[4];
    const float* b2 = (const float*)d_in[5];
    float* out = (float*)d_out;

    int n = in_sizes[0] / 3;
    int e = in_sizes[1] / 2;
    const int* src = ei;
    const int* dst = ei + e;
    const int B = 256;

    int ncb = (n + CB - 1) / CB;
    int nchunk = (e + CHUNK - 1) / CHUNK;
    int gridN2 = (2 * n + B - 1) / B;

    // ws: xs4[n] | t2s[n] | rowptr[n+1] | cntc[ncb] basec[ncb+1]
    //   | hcT[ncb*nchunk] | tmp[e] | tmp2[e]
    size_t needc = (size_t)n * 16 + (size_t)n * 4 + (size_t)(n + 1) * 4
                 + (size_t)(2 * ncb + 1) * 4 + (size_t)ncb * nchunk * 4
                 + (size_t)e * 8 + 64;

    if (ncb <= 256 && n < (1 << 21) && ws_size >= needc) {
        float4* xs4 = (float4*)d_ws;                            // n
        float* t2s = (float*)(xs4 + n);                         // n
        unsigned int* rowptr = (unsigned int*)(t2s + n);        // n+1
        unsigned int* cntc   = rowptr + (n + 1);                // ncb
        unsigned int* basec  = cntc + ncb;                      // ncb+1
        unsigned int* hcT    = basec + ncb + 1;                 // ncb*nchunk
        unsigned int* tmp    = hcT + (size_t)ncb * nchunk;      // e
        unsigned int* tmp2   = tmp + e;                         // e

        k_hist<<<nchunk, B, 0, stream>>>(dst, e, ncb, nchunk, hcT);
        k_scanf<<<ncb, B, 0, stream>>>(hcT, cntc, nchunk);
        k_scanb<<<1, B, 0, stream>>>(cntc, ncb, basec, rowptr, n, (unsigned)e);
        k_fill<<<nchunk, B, 0, stream>>>(src, dst, e, ncb, nchunk, basec, hcT, tmp);
        k_sortC<<<ncb, BT, 0, stream>>>(tmp, basec, x, rowptr, tmp2, xs4, n);
        k_s1<<<gridN2, B, 0, stream>>>(rowptr, tmp2, xs4, W1, b1, W2, b2, t2s, out, n);
        k_s2<<<gridN2, B, 0, stream>>>(rowptr, tmp2, t2s, xs4, out, n);
    } else {
        // split fallback (R10 structure): works for ncb <= NCB_MAX
        int gridN = (n + B - 1) / B;
        float4* xs4 = (float4*)d_ws;
        float* agg0 = (float*)(xs4 + n);
        float* agg1 = agg0 + n;
        float* agg2 = agg1 + n;
        unsigned int* deg = (unsigned int*)(agg2 + n);
        float* t2s = (float*)(deg + n);
        unsigned int* cntc   = (unsigned int*)(t2s + n);
        unsigned int* basec  = cntc + ncb;
        unsigned int* hcT    = basec + ncb + 1;
        unsigned int* tmp    = hcT + (size_t)ncb * nchunk;

        k_zero<<<(4 * n + B - 1) / B, B, 0, stream>>>((unsigned int*)agg0, 4 * n);
        k_hist<<<nchunk, B, 0, stream>>>(dst, e, ncb, nchunk, hcT);
        k_scanf<<<ncb, B, 0, stream>>>(hcT, cntc, nchunk);
        k_scanb<<<1, B, 0, stream>>>(cntc, ncb, basec, (unsigned int*)t2s, 0, (unsigned)e);
        k_fill<<<nchunk, B, 0, stream>>>(src, dst, e, ncb, nchunk, basec, hcT, tmp);
        k_deg_split<<<ncb * SPL, BT, 0, stream>>>(tmp, basec, cntc, deg, n);
        k_inv_s<<<gridN, B, 0, stream>>>(deg, x, xs4, n);
        k_s1_split<<<ncb * SPL, BT, 0, stream>>>(tmp, basec, cntc, xs4, agg0, agg1, agg2, n);
        k_epi_s<<<gridN, B, 0, stream>>>(agg0, agg1, agg2, xs4, W1, b1, W2, b2, t2s, out, n);
        k_s2_split<<<ncb * SPL, BT, 0, stream>>>(tmp, basec, cntc, t2s, xs4, out, n);
    }
}